// Round 1
// baseline (70.377 us; speedup 1.0000x reference)
//
#include <hip/hip_runtime.h>

#define B_  4
#define NQ_ 256
#define NK_ 512
#define H_  256
#define QPB 4

// C[m][n] = sum_k A[m][k] * Bm[n][k]   (both row-major, K-contiguous: "NT" GEMM)
__global__ __launch_bounds__(256)
void gemm_nt(const float* __restrict__ A, const float* __restrict__ Bm,
             float* __restrict__ C, int lda, int ldb, int ldc,
             long sA, long sB, long sC, int K)
{
    constexpr int BM = 64, BN = 64, BK = 32;
    const int bz = blockIdx.z;
    A  += (long)bz * sA;
    Bm += (long)bz * sB;
    C  += (long)bz * sC;
    const int m0 = blockIdx.y * BM, n0 = blockIdx.x * BN;

    __shared__ float As[BK][BM + 4];   // +4 pad: keeps 16B alignment AND rotates banks
    __shared__ float Bs[BK][BN + 4];

    const int tid  = threadIdx.x;
    const int lrow = tid >> 2;          // 0..63 row within tile
    const int lk   = (tid & 3) * 8;     // k offset {0,8,16,24}
    const int tm   = (tid >> 4) * 4;    // 0..60
    const int tn   = (tid & 15) * 4;    // 0..60

    float acc[4][4] = {};

    for (int kt = 0; kt < K; kt += BK) {
        float4 a0 = *(const float4*)&A [(long)(m0 + lrow) * lda + kt + lk];
        float4 a1 = *(const float4*)&A [(long)(m0 + lrow) * lda + kt + lk + 4];
        float4 b0 = *(const float4*)&Bm[(long)(n0 + lrow) * ldb + kt + lk];
        float4 b1 = *(const float4*)&Bm[(long)(n0 + lrow) * ldb + kt + lk + 4];
        __syncthreads();   // previous iteration finished reading LDS
        As[lk+0][lrow]=a0.x; As[lk+1][lrow]=a0.y; As[lk+2][lrow]=a0.z; As[lk+3][lrow]=a0.w;
        As[lk+4][lrow]=a1.x; As[lk+5][lrow]=a1.y; As[lk+6][lrow]=a1.z; As[lk+7][lrow]=a1.w;
        Bs[lk+0][lrow]=b0.x; Bs[lk+1][lrow]=b0.y; Bs[lk+2][lrow]=b0.z; Bs[lk+3][lrow]=b0.w;
        Bs[lk+4][lrow]=b1.x; Bs[lk+5][lrow]=b1.y; Bs[lk+6][lrow]=b1.z; Bs[lk+7][lrow]=b1.w;
        __syncthreads();
        #pragma unroll
        for (int kk = 0; kk < BK; ++kk) {
            float4 av = *(const float4*)&As[kk][tm];
            float4 bv = *(const float4*)&Bs[kk][tn];
            float am[4] = {av.x, av.y, av.z, av.w};
            float bn[4] = {bv.x, bv.y, bv.z, bv.w};
            #pragma unroll
            for (int i = 0; i < 4; ++i)
                #pragma unroll
                for (int j = 0; j < 4; ++j)
                    acc[i][j] = fmaf(am[i], bn[j], acc[i][j]);
        }
    }
    #pragma unroll
    for (int i = 0; i < 4; ++i) {
        float4 o = {acc[i][0], acc[i][1], acc[i][2], acc[i][3]};
        *(float4*)&C[(long)(m0 + tm + i) * ldc + n0 + tn] = o;
    }
}

// One block per (b, 4 consecutive q). 512 threads = one per k.
// prod[b,q,k] = V - 2 * sum_o v[o] * rcp(exp2(c*(ktT[o][k]+qt[q][o])) + 1)
// then log_softmax over k.
__global__ __launch_bounds__(512)
void attn_main(const float* __restrict__ ktT,   // [B][H][NK]
               const float* __restrict__ qt,    // [B][NQ][H]
               const float* __restrict__ v,     // [H]
               float* __restrict__ out)         // [B][NQ][NK]
{
    const int k  = threadIdx.x;          // 0..511
    const int b  = blockIdx.y;
    const int q0 = blockIdx.x * QPB;
    const float* ktb = ktT + (long)b * H_ * NK_;
    const float* qtb = qt  + ((long)b * NQ_ + q0) * H_;   // wave-uniform reads -> s_load

    float acc[QPB] = {};
    float V = 0.f;
    #pragma unroll 4
    for (int h = 0; h < H_; ++h) {
        float kv = ktb[(long)h * NK_ + k];   // coalesced, L2-resident
        float vh = v[h];                      // uniform -> scalar
        V += vh;
        #pragma unroll
        for (int j = 0; j < QPB; ++j) {
            float x = kv + qtb[j * H_ + h];
            float t = __builtin_amdgcn_exp2f(x * 2.885390081777927f); // e^{2x}
            float r = __builtin_amdgcn_rcpf(t + 1.0f);                // overflow-safe
            acc[j]  = fmaf(vh, r, acc[j]);
        }
    }
    float val[QPB];
    #pragma unroll
    for (int j = 0; j < QPB; ++j) val[j] = fmaf(-2.f, acc[j], V);

    // ---- log-softmax over k (block of 512 = 8 waves) ----
    __shared__ float red[8][QPB];
    const int lane = k & 63, wv = k >> 6;
    float m[QPB], s[QPB];

    #pragma unroll
    for (int j = 0; j < QPB; ++j) {
        float x = val[j];
        for (int o = 32; o; o >>= 1) x = fmaxf(x, __shfl_xor(x, o, 64));
        if (lane == 0) red[wv][j] = x;
    }
    __syncthreads();
    #pragma unroll
    for (int j = 0; j < QPB; ++j) {
        float x = red[0][j];
        #pragma unroll
        for (int w = 1; w < 8; ++w) x = fmaxf(x, red[w][j]);
        m[j] = x;
    }
    __syncthreads();
    #pragma unroll
    for (int j = 0; j < QPB; ++j) {
        float e = __builtin_amdgcn_exp2f((val[j] - m[j]) * 1.4426950408889634f);
        for (int o = 32; o; o >>= 1) e += __shfl_xor(e, o, 64);
        if (lane == 0) red[wv][j] = e;
    }
    __syncthreads();
    #pragma unroll
    for (int j = 0; j < QPB; ++j) {
        float ssum = 0.f;
        #pragma unroll
        for (int w = 0; w < 8; ++w) ssum += red[w][j];
        s[j] = ssum;
    }
    #pragma unroll
    for (int j = 0; j < QPB; ++j) {
        float l = __builtin_amdgcn_logf(s[j]) * 0.6931471805599453f;  // ln(s)
        out[((long)(b * NQ_ + q0 + j)) * NK_ + k] = val[j] - m[j] - l;
    }
}

extern "C" void kernel_launch(void* const* d_in, const int* in_sizes, int n_in,
                              void* d_out, int out_size, void* d_ws, size_t ws_size,
                              hipStream_t stream)
{
    const float* xq = (const float*)d_in[0];  // (4,256,256)
    const float* xk = (const float*)d_in[1];  // (4,512,256)
    const float* w1 = (const float*)d_in[2];  // (256,256) out,in
    const float* w2 = (const float*)d_in[3];  // (256,256)
    const float* v  = (const float*)d_in[4];  // (1,256)
    float* out = (float*)d_out;

    float* ktT = (float*)d_ws;                           // [4][256][512] = 2 MB
    float* qt  = ktT + (size_t)B_ * H_ * NK_;            // [4][256][256] = 1 MB

    // ktT[b][o][k] = sum_h w1[o][h] * xk[b][k][h]
    gemm_nt<<<dim3(NK_ / 64, H_ / 64, B_), 256, 0, stream>>>(
        w1, xk, ktT, H_, H_, NK_, 0L, (long)NK_ * H_, (long)H_ * NK_, H_);

    // qt[b][q][o] = sum_h xq[b][q][h] * w2[o][h]
    gemm_nt<<<dim3(H_ / 64, NQ_ / 64, B_), 256, 0, stream>>>(
        xq, w2, qt, H_, H_, H_, (long)NQ_ * H_, 0L, (long)NQ_ * H_, H_);

    attn_main<<<dim3(NQ_ / QPB, B_), 512, 0, stream>>>(ktT, qt, v, out);
}

// Round 2
// 54.796 us; speedup vs baseline: 1.2843x; 1.2843x over previous
//
#include <hip/hip_runtime.h>

#define B_  4
#define NQ_ 256
#define NK_ 512
#define H_  256
#define QPB 2

// 2*log2(e): folded into GEMM epilogue so attn's exp2 arg needs no scaling
#define C_SCALE 2.8853900817779268f

// Both small GEMMs in ONE launch. 192 blocks of 256 threads, 64x64 tiles.
// blocks [0,128): ktT[b][o][k] = C_SCALE * sum_h w1[o][h] * xk[b][k][h]
// blocks [128,192): qt[b][q][o] = C_SCALE * sum_h xq[b][q][h] * w2[o][h]
__global__ __launch_bounds__(256)
void gemm_fused(const float* __restrict__ xq, const float* __restrict__ xk,
                const float* __restrict__ w1, const float* __restrict__ w2,
                float* __restrict__ ktT, float* __restrict__ qt)
{
    constexpr int BK = 32;
    const float* A; const float* Bm; float* C;
    int ldc, m0, n0;
    {
        int id = blockIdx.x;
        if (id < 128) {                      // kt problem
            int b = id >> 5, t = id & 31;
            n0 = (t & 7) * 64; m0 = (t >> 3) * 64;
            A = w1; Bm = xk + (long)b * NK_ * H_; C = ktT + (long)b * H_ * NK_;
            ldc = NK_;
        } else {                             // qt problem
            id -= 128;
            int b = id >> 4, t = id & 15;
            n0 = (t & 3) * 64; m0 = (t >> 2) * 64;
            A = xq + (long)b * NQ_ * H_; Bm = w2; C = qt + (long)b * NQ_ * H_;
            ldc = H_;
        }
    }
    const int lda = H_, ldb = H_;

    __shared__ float As[BK][64 + 4];
    __shared__ float Bs[BK][64 + 4];

    const int tid  = threadIdx.x;
    const int lrow = tid >> 2;          // 0..63
    const int lk   = (tid & 3) * 8;     // {0,8,16,24}
    const int tm   = (tid >> 4) * 4;
    const int tn   = (tid & 15) * 4;

    float acc[4][4] = {};

    for (int kt = 0; kt < H_; kt += BK) {
        float4 a0 = *(const float4*)&A [(long)(m0 + lrow) * lda + kt + lk];
        float4 a1 = *(const float4*)&A [(long)(m0 + lrow) * lda + kt + lk + 4];
        float4 b0 = *(const float4*)&Bm[(long)(n0 + lrow) * ldb + kt + lk];
        float4 b1 = *(const float4*)&Bm[(long)(n0 + lrow) * ldb + kt + lk + 4];
        __syncthreads();
        As[lk+0][lrow]=a0.x; As[lk+1][lrow]=a0.y; As[lk+2][lrow]=a0.z; As[lk+3][lrow]=a0.w;
        As[lk+4][lrow]=a1.x; As[lk+5][lrow]=a1.y; As[lk+6][lrow]=a1.z; As[lk+7][lrow]=a1.w;
        Bs[lk+0][lrow]=b0.x; Bs[lk+1][lrow]=b0.y; Bs[lk+2][lrow]=b0.z; Bs[lk+3][lrow]=b0.w;
        Bs[lk+4][lrow]=b1.x; Bs[lk+5][lrow]=b1.y; Bs[lk+6][lrow]=b1.z; Bs[lk+7][lrow]=b1.w;
        __syncthreads();
        #pragma unroll
        for (int kk = 0; kk < BK; ++kk) {
            float4 av = *(const float4*)&As[kk][tm];
            float4 bv = *(const float4*)&Bs[kk][tn];
            float am[4] = {av.x, av.y, av.z, av.w};
            float bn[4] = {bv.x, bv.y, bv.z, bv.w};
            #pragma unroll
            for (int i = 0; i < 4; ++i)
                #pragma unroll
                for (int j = 0; j < 4; ++j)
                    acc[i][j] = fmaf(am[i], bn[j], acc[i][j]);
        }
    }
    #pragma unroll
    for (int i = 0; i < 4; ++i) {
        float4 o = {acc[i][0] * C_SCALE, acc[i][1] * C_SCALE,
                    acc[i][2] * C_SCALE, acc[i][3] * C_SCALE};
        *(float4*)&C[(long)(m0 + tm + i) * ldc + n0 + tn] = o;
    }
}

// One block per (b, QPB q-rows). 512 threads = one per k. Inputs pre-scaled by
// 2*log2e, so: tanh-term = 1 - 2*rcp(exp2(kv+qv)+1);
// prod = V - 2*sum_h v[h]*rcp(...); then log_softmax over k.
__global__ __launch_bounds__(512)
void attn_main(const float* __restrict__ ktT,   // [B][H][NK], pre-scaled
               const float* __restrict__ qt,    // [B][NQ][H], pre-scaled
               const float* __restrict__ v,     // [H]
               float* __restrict__ out)         // [B][NQ][NK]
{
    const int k  = threadIdx.x;          // 0..511
    const int b  = blockIdx.y;
    const int q0 = blockIdx.x * QPB;
    const float* ktb = ktT + (long)b * H_ * NK_;
    const float* qtb = qt  + ((long)b * NQ_ + q0) * H_;   // wave-uniform -> s_load

    float acc[QPB] = {};
    float V = 0.f;
    #pragma unroll 4
    for (int h = 0; h < H_; ++h) {
        float kv = ktb[(long)h * NK_ + k];   // coalesced, L2-resident
        float vh = v[h];                      // uniform -> scalar
        V += vh;
        #pragma unroll
        for (int j = 0; j < QPB; ++j) {
            float t = __builtin_amdgcn_exp2f(kv + qtb[j * H_ + h]);
            float r = __builtin_amdgcn_rcpf(t + 1.0f);   // overflow-safe
            acc[j]  = fmaf(vh, r, acc[j]);
        }
    }
    float val[QPB];
    #pragma unroll
    for (int j = 0; j < QPB; ++j) val[j] = fmaf(-2.f, acc[j], V);

    // ---- log-softmax over k (512 threads = 8 waves) ----
    __shared__ float red[8][QPB];
    const int lane = k & 63, wv = k >> 6;
    float m[QPB], s[QPB];

    #pragma unroll
    for (int j = 0; j < QPB; ++j) {
        float x = val[j];
        for (int o = 32; o; o >>= 1) x = fmaxf(x, __shfl_xor(x, o, 64));
        if (lane == 0) red[wv][j] = x;
    }
    __syncthreads();
    #pragma unroll
    for (int j = 0; j < QPB; ++j) {
        float x = red[0][j];
        #pragma unroll
        for (int w = 1; w < 8; ++w) x = fmaxf(x, red[w][j]);
        m[j] = x;
    }
    __syncthreads();
    #pragma unroll
    for (int j = 0; j < QPB; ++j) {
        float e = __builtin_amdgcn_exp2f((val[j] - m[j]) * 1.4426950408889634f);
        for (int o = 32; o; o >>= 1) e += __shfl_xor(e, o, 64);
        if (lane == 0) red[wv][j] = e;
    }
    __syncthreads();
    #pragma unroll
    for (int j = 0; j < QPB; ++j) {
        float ssum = 0.f;
        #pragma unroll
        for (int w = 0; w < 8; ++w) ssum += red[w][j];
        s[j] = ssum;
    }
    #pragma unroll
    for (int j = 0; j < QPB; ++j) {
        float l = __builtin_amdgcn_logf(s[j]) * 0.6931471805599453f;  // ln(s)
        out[((long)(b * NQ_ + q0 + j)) * NK_ + k] = val[j] - m[j] - l;
    }
}

extern "C" void kernel_launch(void* const* d_in, const int* in_sizes, int n_in,
                              void* d_out, int out_size, void* d_ws, size_t ws_size,
                              hipStream_t stream)
{
    const float* xq = (const float*)d_in[0];  // (4,256,256)
    const float* xk = (const float*)d_in[1];  // (4,512,256)
    const float* w1 = (const float*)d_in[2];  // (256,256) out,in
    const float* w2 = (const float*)d_in[3];  // (256,256)
    const float* v  = (const float*)d_in[4];  // (1,256)
    float* out = (float*)d_out;

    float* ktT = (float*)d_ws;                           // [4][256][512] = 2 MB
    float* qt  = ktT + (size_t)B_ * H_ * NK_;            // [4][256][256] = 1 MB

    gemm_fused<<<dim3(192), 256, 0, stream>>>(xq, xk, w1, w2, ktT, qt);
    attn_main<<<dim3(NQ_ / QPB, B_), 512, 0, stream>>>(ktT, qt, v, out);
}